// Round 15
// baseline (1385.354 us; speedup 1.0000x reference)
//
#include <hip/hip_runtime.h>
#include <hip/hip_bf16.h>

#define B_   2
#define T_   2048
#define D_   2048
#define H_   16
#define DH_  128
#define TD3_ 6144   // 3*D

typedef __attribute__((ext_vector_type(8))) short   short8;
typedef __attribute__((ext_vector_type(8))) unsigned short ushort8v;
typedef __attribute__((ext_vector_type(4))) float   f32x4;
typedef __attribute__((ext_vector_type(4))) float   f4v;
typedef __attribute__((ext_vector_type(4))) unsigned short u16x4;

static __device__ __forceinline__ unsigned short f2bf(float f) {
  unsigned int u = __builtin_bit_cast(unsigned int, f);
  u += 0x7FFFu + ((u >> 16) & 1u);
  return (unsigned short)(u >> 16);
}
static __device__ __forceinline__ float bf2f(unsigned short u) {
  return __builtin_bit_cast(float, (unsigned int)u << 16);
}
static __device__ __forceinline__ float fexp2(float x) {
  float r; asm("v_exp_f32 %0, %1" : "=v"(r) : "v"(x)); return r;
}

static __device__ __forceinline__ void gload_lds16(const unsigned short* g, unsigned short* l) {
  __builtin_amdgcn_global_load_lds((const __attribute__((address_space(1))) void*)g,
                                   (__attribute__((address_space(3))) void*)l, 16, 0, 0);
}

// ---------------- fp32 -> bf16 elementwise cast (vectorized) ----------------
__global__ __launch_bounds__(256) void convert_f32_bf16(const float* __restrict__ X,
                                                        unsigned short* __restrict__ Y, int n4) {
  for (int i = blockIdx.x * blockDim.x + threadIdx.x; i < n4; i += gridDim.x * blockDim.x) {
    f4v v = ((const f4v*)X)[i];
    u16x4 o;
    o[0] = f2bf(v[0]); o[1] = f2bf(v[1]); o[2] = f2bf(v[2]); o[3] = f2bf(v[3]);
    ((u16x4*)Y)[i] = o;
  }
}

// ---------------- transpose fp32 [K][N] -> bf16 [N][K] ----------------
__global__ __launch_bounds__(256) void transpose_f32_bf16(const float* __restrict__ W,
                                                          unsigned short* __restrict__ WT,
                                                          int K, int N) {
  __shared__ float tile[32][33];
  int n0 = blockIdx.x * 32, k0 = blockIdx.y * 32;
  int tx = threadIdx.x & 31, ty = threadIdx.x >> 5;
#pragma unroll
  for (int r = 0; r < 4; r++)
    tile[ty + 8 * r][tx] = W[(size_t)(k0 + ty + 8 * r) * N + n0 + tx];
  __syncthreads();
#pragma unroll
  for (int r = 0; r < 4; r++)
    WT[(size_t)(n0 + ty + 8 * r) * K + k0 + tx] = f2bf(tile[tx][ty + 8 * r]);
}

// ---------------- V transpose: qkv V-third [b][t][h*DH+dh] -> vtg [b][h][dh][t] ----------------
__global__ __launch_bounds__(256) void vtr_kernel(const unsigned short* __restrict__ qkv,
                                                  unsigned short* __restrict__ vtg) {
  __shared__ unsigned short tile[64][68];
  const int t0 = blockIdx.x * 64;
  const int h = blockIdx.y >> 1, dh0 = (blockIdx.y & 1) * 64;
  const int b = blockIdx.z;
  const int tid = threadIdx.x;
  const unsigned short* src = qkv + (size_t)b * T_ * TD3_ + 2 * D_ + h * DH_ + dh0;
  {
    const int r = tid >> 3, cc = (tid & 7) * 8;
#pragma unroll
    for (int k = 0; k < 2; k++) {
      ushort8v v = *(const ushort8v*)(src + (size_t)(t0 + k * 32 + r) * TD3_ + cc);
      *(ushort8v*)&tile[k * 32 + r][cc] = v;
    }
  }
  __syncthreads();
  unsigned short* dst = vtg + ((size_t)(b * H_ + h) * DH_ + dh0) * T_ + t0;
  {
    const int d = tid >> 3, tc = (tid & 7) * 8;
#pragma unroll
    for (int k = 0; k < 2; k++) {
      ushort8v v;
#pragma unroll
      for (int j = 0; j < 8; j++) v[j] = tile[tc + j][k * 32 + d];
      *(ushort8v*)(dst + (size_t)(k * 32 + d) * T_ + tc) = v;
    }
  }
}

// ---------------- 256x192 single-barrier bf16 GEMM (QKV): C bf16 ----------------
// A staged in LDS (64 KiB, 2 blocks/CU); B read DIRECTLY from L2 into registers,
// prefetched one full tile ahead (XCD-chunked map keeps the 3 MB B panel L2-resident).
// ONE barrier per K-tile (mid-PH_B after vmcnt(0)) -- only hazard-carrying sync.
__global__ __launch_bounds__(512, 4) void gemm_qkv192(const unsigned short* __restrict__ A,
                                                      const unsigned short* __restrict__ BT,
                                                      unsigned short* __restrict__ C,
                                                      int M, int N, int K) {
  __shared__ unsigned short lA[2][2][128 * 64];   // 64 KiB

  const int tid = threadIdx.x;
  const int bid = (int)blockIdx.x;
  const int npx = 4;                              // n-tiles per XCD
  const int xcd = bid & 7, idx = bid >> 3;
  const int n0 = (xcd * npx + (idx & 3)) * 192;
  const int m0 = (idx >> 2) * 256;
  const int l = tid & 63, lr = l & 15, lg = l >> 4;
  const int wid = tid >> 6, wm = wid >> 2, wn = wid & 3;
  const int nk = K >> 6;                          // 32 (even; kt+=2 unroll relies on it)

  f32x4 acc[8][3] = {};
  short8 aQ0[4][2], aQ1[4][2], bX[3][2], bY[3][2];

  const unsigned short* Bbase = BT + (size_t)(n0 + wn * 48 + lr) * K + lg * 8;

  auto stageA = [&](int buf, int h, int kt) {
#pragma unroll
    for (int q = 0; q < 2; q++) {
      const int n = q * 512 + tid;
      const int row = n >> 3, ch = n & 7;
      gload_lds16(A + (size_t)(m0 + h * 128 + row) * K + kt * 64 + ((ch ^ (row & 7)) << 3),
                  &lA[buf][h][n * 8]);
    }
  };
  auto bldB = [&](short8 (*DST)[2], int kt) {    // B frags: global(L2) -> regs, no swizzle
#pragma unroll
    for (int ni = 0; ni < 3; ni++)
#pragma unroll
      for (int kk = 0; kk < 2; kk++)
        DST[ni][kk] = *(const short8*)(Bbase + (size_t)(ni * 16) * K + kt * 64 + kk * 32);
  };

#define QKV_READ_A(DST, BUF, QUAD)                                              \
  _Pragma("unroll")                                                             \
  for (int mi = 0; mi < 4; mi++)                                                \
    _Pragma("unroll")                                                           \
    for (int kk = 0; kk < 2; kk++) {                                            \
      const int row = ((QUAD) * 4 + mi) * 16 + lr;                              \
      DST[mi][kk] = *(const short8*)&lA[BUF][wm][row * 64 +                     \
                      (((kk * 4 + lg) ^ (lr & 7)) << 3)];                       \
    }

// PH_A(t): stage A(t+1)->buf^1; load B(t+1)->regs; read aQ1(buf); 24 MFMA. NO barrier.
#define QKV_PHASE_A(BUF, BCUR, BNXT, TT)                                        \
  {                                                                             \
    if ((TT) + 1 < nk) {                                                        \
      stageA(1 - (BUF), 0, (TT) + 1); stageA(1 - (BUF), 1, (TT) + 1);           \
      bldB(BNXT, (TT) + 1);                                                     \
    }                                                                           \
    QKV_READ_A(aQ1, BUF, 1)                                                     \
    __builtin_amdgcn_s_setprio(1);                                              \
    _Pragma("unroll")                                                           \
    for (int mi = 0; mi < 4; mi++)                                              \
      _Pragma("unroll")                                                         \
      for (int ni = 0; ni < 3; ni++)                                            \
        _Pragma("unroll")                                                       \
        for (int kk = 0; kk < 2; kk++)                                          \
          acc[mi][ni] = __builtin_amdgcn_mfma_f32_16x16x32_bf16(                \
              aQ0[mi][kk], BCUR[ni][kk], acc[mi][ni], 0, 0, 0);                 \
    __builtin_amdgcn_s_setprio(0);                                              \
  }

// PH_B(t): 16 MFMA; vmcnt(0); THE barrier; prefetch aQ0(t+1); 8 MFMA. NO trailing barrier.
#define QKV_PHASE_B(BUF, BCUR, TT)                                              \
  {                                                                             \
    __builtin_amdgcn_s_setprio(1);                                              \
    _Pragma("unroll")                                                           \
    for (int mi = 0; mi < 4; mi++)                                              \
      _Pragma("unroll")                                                         \
      for (int ni = 0; ni < 2; ni++)                                            \
        _Pragma("unroll")                                                       \
        for (int kk = 0; kk < 2; kk++)                                          \
          acc[4 + mi][ni] = __builtin_amdgcn_mfma_f32_16x16x32_bf16(            \
              aQ1[mi][kk], BCUR[ni][kk], acc[4 + mi][ni], 0, 0, 0);             \
    __builtin_amdgcn_s_setprio(0);                                              \
    asm volatile("s_waitcnt vmcnt(0)" ::: "memory");                            \
    __builtin_amdgcn_s_barrier();                                               \
    __builtin_amdgcn_sched_barrier(0);                                          \
    if ((TT) + 1 < nk) {                                                        \
      QKV_READ_A(aQ0, 1 - (BUF), 0)                                             \
    }                                                                           \
    __builtin_amdgcn_s_setprio(1);                                              \
    _Pragma("unroll")                                                           \
    for (int mi = 0; mi < 4; mi++)                                              \
      _Pragma("unroll")                                                         \
      for (int kk = 0; kk < 2; kk++)                                            \
        acc[4 + mi][2] = __builtin_amdgcn_mfma_f32_16x16x32_bf16(               \
            aQ1[mi][kk], BCUR[2][kk], acc[4 + mi][2], 0, 0, 0);                 \
    __builtin_amdgcn_s_setprio(0);                                              \
  }

  // ---- prologue: stage tile0 A, load tile0 B, drain, load tile0 A-frags ----
  stageA(0, 0, 0); stageA(0, 1, 0);
  bldB(bX, 0);
  asm volatile("s_waitcnt vmcnt(0)" ::: "memory");
  __builtin_amdgcn_s_barrier();
  __builtin_amdgcn_sched_barrier(0);
  QKV_READ_A(aQ0, 0, 0)

  for (int kt = 0; kt < nk; kt += 2) {
    QKV_PHASE_A(0, bX, bY, kt)
    QKV_PHASE_B(0, bX, kt)
    QKV_PHASE_A(1, bY, bX, kt + 1)
    QKV_PHASE_B(1, bY, kt + 1)
  }

#pragma unroll
  for (int mi = 0; mi < 8; mi++)
#pragma unroll
    for (int ni = 0; ni < 3; ni++)
#pragma unroll
      for (int i = 0; i < 4; i++) {
        const int row = m0 + wm * 128 + mi * 16 + lg * 4 + i;
        const int col = n0 + wn * 48 + ni * 16 + lr;
        C[(size_t)row * N + col] = f2bf(acc[mi][ni][i]);
      }
#undef QKV_PHASE_B
#undef QKV_PHASE_A
#undef QKV_READ_A
}

// ---------------- 128x256 single-barrier bf16 GEMM (output proj): C fp32 ----------------
// Same single-barrier structure (mid-PH_B vmcnt(0)+barrier is the only hazard sync).
__global__ __launch_bounds__(512, 1) void gemm_op8(const unsigned short* __restrict__ A,
                                                   const unsigned short* __restrict__ BT,
                                                   float* __restrict__ C,
                                                   int M, int N, int K) {
  __shared__ unsigned short lA[2][128 * 64];      // 32 KiB
  __shared__ unsigned short lB[2][2][128 * 64];   // 64 KiB

  const int tid = threadIdx.x;
  const int bid = (int)blockIdx.x;
  const int xcd = bid & 7, idx = bid >> 3;        // N/256 == 8 n-tiles: one per XCD
  const int n0 = xcd * 256, m0 = idx * 128;
  const int l = tid & 63, lr = l & 15, lg = l >> 4;
  const int wid = tid >> 6, wm = wid >> 2, wn = wid & 3;
  const int bh = wn >> 1, br0 = (wn & 1) * 64;
  const int nk = K >> 6;                          // 32 (even)

  f32x4 acc[4][4] = {};
  short8 aLO[2][2], aHI[2][2], b[4][2];

  auto stageA = [&](int buf, int kt) {
#pragma unroll
    for (int q = 0; q < 2; q++) {
      const int n = q * 512 + tid;
      const int row = n >> 3, ch = n & 7;
      gload_lds16(A + (size_t)(m0 + row) * K + kt * 64 + ((ch ^ (row & 7)) << 3),
                  &lA[buf][n * 8]);
    }
  };
  auto stageB = [&](int buf, int h, int kt) {
#pragma unroll
    for (int q = 0; q < 2; q++) {
      const int n = q * 512 + tid;
      const int row = n >> 3, ch = n & 7;
      gload_lds16(BT + (size_t)(n0 + h * 128 + row) * K + kt * 64 + ((ch ^ (row & 7)) << 3),
                  &lB[buf][h][n * 8]);
    }
  };

#define OP_STAGE_ALL(BUF, TT)                                                   \
  { stageB(BUF, 0, TT); stageB(BUF, 1, TT); stageA(BUF, TT); }

#define OP_READ_A(DST, BUF, HALF)                                               \
  _Pragma("unroll")                                                             \
  for (int mi = 0; mi < 2; mi++)                                                \
    _Pragma("unroll")                                                           \
    for (int kk = 0; kk < 2; kk++) {                                            \
      const int row = wm * 64 + ((HALF) * 2 + mi) * 16 + lr;                    \
      DST[mi][kk] = *(const short8*)&lA[BUF][row * 64 +                         \
                      (((kk * 4 + lg) ^ (lr & 7)) << 3)];                       \
    }

#define OP_READ_B(BUF)                                                          \
  _Pragma("unroll")                                                             \
  for (int ni = 0; ni < 4; ni++)                                                \
    _Pragma("unroll")                                                           \
    for (int kk = 0; kk < 2; kk++) {                                            \
      const int row = br0 + ni * 16 + lr;                                       \
      b[ni][kk] = *(const short8*)&lB[BUF][bh][row * 64 +                       \
                      (((kk * 4 + lg) ^ (lr & 7)) << 3)];                       \
    }

  // ---- prologue ----
  OP_STAGE_ALL(0, 0)
  asm volatile("s_waitcnt vmcnt(0)" ::: "memory");
  __builtin_amdgcn_s_barrier();
  __builtin_amdgcn_sched_barrier(0);
  OP_READ_A(aLO, 0, 0)
  OP_READ_B(0)

  for (int kt = 0; kt < nk; kt++) {
    const int buf = kt & 1;

    // PH_A: stage all (t+1)->buf^1; read aHI(buf); 16 MFMA (aLO x b[0..3]). NO barrier.
    if (kt + 1 < nk) OP_STAGE_ALL(buf ^ 1, kt + 1)
    OP_READ_A(aHI, buf, 1)
    __builtin_amdgcn_s_setprio(1);
#pragma unroll
    for (int mi = 0; mi < 2; mi++)
#pragma unroll
      for (int ni = 0; ni < 4; ni++)
#pragma unroll
        for (int kk = 0; kk < 2; kk++)
          acc[mi][ni] = __builtin_amdgcn_mfma_f32_16x16x32_bf16(aLO[mi][kk], b[ni][kk], acc[mi][ni], 0, 0, 0);
    __builtin_amdgcn_s_setprio(0);

    // PH_B: 8 MFMA (aHI x b[0..1]); vmcnt(0); THE barrier; prefetch (t+1) frags;
    //       8 MFMA (aHI x b[2..3]). NO trailing barrier.
    __builtin_amdgcn_s_setprio(1);
#pragma unroll
    for (int mi = 0; mi < 2; mi++)
#pragma unroll
      for (int ni = 0; ni < 2; ni++)
#pragma unroll
        for (int kk = 0; kk < 2; kk++)
          acc[2 + mi][ni] = __builtin_amdgcn_mfma_f32_16x16x32_bf16(aHI[mi][kk], b[ni][kk], acc[2 + mi][ni], 0, 0, 0);
    __builtin_amdgcn_s_setprio(0);
    asm volatile("s_waitcnt vmcnt(0)" ::: "memory");
    __builtin_amdgcn_s_barrier();
    __builtin_amdgcn_sched_barrier(0);
    short8 bsav2[2][2];
#pragma unroll
    for (int ni = 0; ni < 2; ni++)
#pragma unroll
      for (int kk = 0; kk < 2; kk++) bsav2[ni][kk] = b[2 + ni][kk];
    if (kt + 1 < nk) {
      OP_READ_A(aLO, buf ^ 1, 0)
      OP_READ_B(buf ^ 1)
    }
    __builtin_amdgcn_s_setprio(1);
#pragma unroll
    for (int mi = 0; mi < 2; mi++)
#pragma unroll
      for (int ni = 0; ni < 2; ni++)
#pragma unroll
        for (int kk = 0; kk < 2; kk++)
          acc[2 + mi][2 + ni] = __builtin_amdgcn_mfma_f32_16x16x32_bf16(aHI[mi][kk], bsav2[ni][kk], acc[2 + mi][2 + ni], 0, 0, 0);
    __builtin_amdgcn_s_setprio(0);
  }

#pragma unroll
  for (int mi = 0; mi < 4; mi++)
#pragma unroll
    for (int ni = 0; ni < 4; ni++)
#pragma unroll
      for (int i = 0; i < 4; i++) {
        const int row = m0 + wm * 64 + mi * 16 + lg * 4 + i;
        const int col = n0 + wn * 64 + ni * 16 + lr;
        C[(size_t)row * N + col] = acc[mi][ni][i];
      }
#undef OP_READ_B
#undef OP_READ_A
#undef OP_STAGE_ALL
}

// ---------------- flash attention (causal), QBLK=128, KVBLK=64, 2-phase pipeline ----------------
__global__ __launch_bounds__(256, 2) void attn_fa(const unsigned short* __restrict__ qkv,
                                                  const unsigned short* __restrict__ vtg,
                                                  unsigned short* __restrict__ out) {
  const int x = blockIdx.x, h = blockIdx.y, b = blockIdx.z;
  const int qtl = b ? x : (T_ / 128 - 1 - x);
  const int q0 = qtl * 128;
  const int tid = threadIdx.x, w = tid >> 6, l = tid & 63, lr = l & 15, lg = l >> 4;

  const unsigned short* Qb = qkv + (size_t)b * T_ * TD3_ + h * DH_;
  const unsigned short* Kb = Qb + D_;
  const unsigned short* Vt = vtg + ((size_t)b * H_ + h) * DH_ * T_;

  __shared__ unsigned short klds[2][64 * 128];
  __shared__ unsigned short vt[2][128 * 64];
  __shared__ unsigned short plds[4][32 * 64];

  const float scale2 = 0.12751744519764462f;     // log2(e)/sqrt(128)

  short8 qf[2][4];
#pragma unroll
  for (int mi = 0; mi < 2; mi++) {
    const unsigned short* qrow = Qb + (size_t)(q0 + w * 32 + mi * 16 + lr) * TD3_;
#pragma unroll
    for (int ks = 0; ks < 4; ks++) {
      ushort8v qv = *(const ushort8v*)(qrow + ks * 32 + lg * 8);
      short8 qs;
#pragma unroll
      for (int j = 0; j < 8; j++) qs[j] = (short)f2bf(bf2f(qv[j]) * scale2);
      qf[mi][ks] = qs;
    }
  }

  f32x4 oacc[2][8] = {};
  float mrun[2][4], rsuml[2][4];
#pragma unroll
  for (int mi = 0; mi < 2; mi++)
#pragma unroll
    for (int i = 0; i < 4; i++) { mrun[mi][i] = -__builtin_inff(); rsuml[mi][i] = 0.f; }

  auto STAGE = [&](int buf, int kv0) {
#pragma unroll
    for (int it = 0; it < 4; it++) {
      const int n = it * 256 + tid;
      { const int kv = n >> 4, ch = n & 15;
        gload_lds16(Kb + (size_t)(kv0 + kv) * TD3_ + ((ch ^ (kv & 7)) << 3),
                    &klds[buf][n * 8]); }
      { const int dh = n >> 3, ch = n & 7;
        gload_lds16(Vt + (size_t)dh * T_ + kv0 + ((ch ^ (dh & 7)) << 3),
                    &vt[buf][n * 8]); }
    }
  };

  const int nt = 2 * qtl + 2;
  STAGE(0, 0);
  __syncthreads();

  for (int t = 0; t < nt; t++) {
    const int buf = t & 1;
    if (t + 1 < nt) STAGE(buf ^ 1, (t + 1) * 64);

    const int kv0 = t * 64;
    const bool active = (kv0 <= q0 + w * 32 + 31);
    if (active) {
      // ---- S = Q K^T (log2 domain) ----
      f32x4 s[2][4] = {};
      __builtin_amdgcn_s_setprio(1);
#pragma unroll
      for (int nf = 0; nf < 4; nf++) {
        const int kv = nf * 16 + lr;
#pragma unroll
        for (int ks = 0; ks < 4; ks++) {
          short8 kf = *(const short8*)&klds[buf][kv * 128 + (((ks * 4 + lg) ^ (lr & 7)) << 3)];
#pragma unroll
          for (int mi = 0; mi < 2; mi++)
            s[mi][nf] = __builtin_amdgcn_mfma_f32_16x16x32_bf16(qf[mi][ks], kf, s[mi][nf], 0, 0, 0);
        }
      }
      __builtin_amdgcn_s_setprio(0);

      // ---- causal mask + per-lane max ----
      const bool needmask = (kv0 + 63 > q0 + w * 32);
      float pmax[2][4];
#pragma unroll
      for (int mi = 0; mi < 2; mi++)
#pragma unroll
        for (int i = 0; i < 4; i++) pmax[mi][i] = -__builtin_inff();
#pragma unroll
      for (int mi = 0; mi < 2; mi++)
#pragma unroll
        for (int nf = 0; nf < 4; nf++)
#pragma unroll
          for (int i = 0; i < 4; i++) {
            float xv = s[mi][nf][i];
            if (needmask) {
              const int qr = w * 32 + mi * 16 + lg * 4 + i;
              const int kc = nf * 16 + lr;
              if (kv0 + kc > q0 + qr) xv = -__builtin_inff();
            }
            s[mi][nf][i] = xv;
            pmax[mi][i] = fmaxf(pmax[mi][i], xv);
          }

      // ---- defer-max ----
      int ok = 1;
#pragma unroll
      for (int mi = 0; mi < 2; mi++)
#pragma unroll
        for (int i = 0; i < 4; i++)
          ok &= (pmax[mi][i] <= mrun[mi][i] + 8.0f) ? 1 : 0;

      if (!__all(ok)) {
#pragma unroll
        for (int m = 1; m < 16; m <<= 1)
#pragma unroll
          for (int mi = 0; mi < 2; mi++)
#pragma unroll
            for (int i = 0; i < 4; i++)
              pmax[mi][i] = fmaxf(pmax[mi][i], __shfl_xor(pmax[mi][i], m));
#pragma unroll
        for (int mi = 0; mi < 2; mi++)
#pragma unroll
          for (int i = 0; i < 4; i++) {
            const float mn = fmaxf(mrun[mi][i], pmax[mi][i]);
            const float al = fexp2(mrun[mi][i] - mn);
            mrun[mi][i] = mn;
            rsuml[mi][i] *= al;
#pragma unroll
            for (int nf = 0; nf < 8; nf++) oacc[mi][nf][i] *= al;
          }
      }

      // ---- P = exp2(S - m); per-lane rsum; P -> LDS ----
#pragma unroll
      for (int mi = 0; mi < 2; mi++)
#pragma unroll
        for (int nf = 0; nf < 4; nf++)
#pragma unroll
          for (int i = 0; i < 4; i++) {
            const float p = fexp2(s[mi][nf][i] - mrun[mi][i]);
            rsuml[mi][i] += p;
            const int prow = mi * 16 + lg * 4 + i;
            plds[w][prow * 64 + ((nf * 16 + lr) ^ ((prow & 7) << 3))] = f2bf(p);
          }

      // ---- O += P V ----
      __builtin_amdgcn_s_setprio(1);
#pragma unroll
      for (int kk = 0; kk < 2; kk++) {
        short8 pa[2];
#pragma unroll
        for (int mi = 0; mi < 2; mi++) {
          const int prow = mi * 16 + lr;
          pa[mi] = *(const short8*)&plds[w][prow * 64 + (((kk * 32 + lg * 8)) ^ ((prow & 7) << 3))];
        }
#pragma unroll
        for (int nf = 0; nf < 8; nf++) {
          const short8 vb = *(const short8*)&vt[buf][(nf * 16 + lr) * 64 + (((kk * 4 + lg) ^ (lr & 7)) << 3)];
#pragma unroll
          for (int mi = 0; mi < 2; mi++)
            oacc[mi][nf] = __builtin_amdgcn_mfma_f32_16x16x32_bf16(pa[mi], vb, oacc[mi][nf], 0, 0, 0);
        }
      }
      __builtin_amdgcn_s_setprio(0);
    }
    __syncthreads();
  }

  // ---- final rsum reduce + normalize + write ----
#pragma unroll
  for (int m = 1; m < 16; m <<= 1)
#pragma unroll
    for (int mi = 0; mi < 2; mi++)
#pragma unroll
      for (int i = 0; i < 4; i++) rsuml[mi][i] += __shfl_xor(rsuml[mi][i], m);

  float rinv[2][4];
#pragma unroll
  for (int mi = 0; mi < 2; mi++)
#pragma unroll
    for (int i = 0; i < 4; i++) rinv[mi][i] = 1.f / rsuml[mi][i];
#pragma unroll
  for (int mi = 0; mi < 2; mi++) {
    unsigned short* orow = out + ((size_t)b * T_ + q0 + w * 32 + mi * 16 + lg * 4) * D_ + h * DH_;
#pragma unroll
    for (int nf = 0; nf < 8; nf++)
#pragma unroll
      for (int i = 0; i < 4; i++)
        orow[(size_t)i * D_ + nf * 16 + lr] = f2bf(oacc[mi][nf][i] * rinv[mi][i]);
  }
}

extern "C" void kernel_launch(void* const* d_in, const int* in_sizes, int n_in,
                              void* d_out, int out_size, void* d_ws, size_t ws_size,
                              hipStream_t stream) {
  const float* x    = (const float*)d_in[0];
  const float* wqkv = (const float*)d_in[1];
  const float* wo   = (const float*)d_in[2];
  float* out = (float*)d_out;

  char* ws = (char*)d_ws;
  unsigned short* xb    = (unsigned short*)(ws);               // 16.8 MB (reused as attn out)
  unsigned short* wqkvt = (unsigned short*)(ws + 16777216);    // 25.2 MB (dead after gemm1)
  unsigned short* vtg   = (unsigned short*)(ws + 16777216);    // 16.8 MB, overlays wqkvt
  unsigned short* wot   = (unsigned short*)(ws + 41943040);    //  8.4 MB
  unsigned short* qkv   = (unsigned short*)(ws + 50331648);    // 50.3 MB  (end 100.7 MB)
  unsigned short* attn  = xb;   // xb dead after GEMM1

  convert_f32_bf16<<<2048, 256, 0, stream>>>(x, xb, B_ * T_ * D_ / 4);
  transpose_f32_bf16<<<dim3(TD3_ / 32, D_ / 32), 256, 0, stream>>>(wqkv, wqkvt, D_, TD3_);
  transpose_f32_bf16<<<dim3(D_ / 32, D_ / 32), 256, 0, stream>>>(wo, wot, D_, D_);

  gemm_qkv192<<<dim3(512), 512, 0, stream>>>(xb, wqkvt, qkv, B_ * T_, TD3_, D_);
  vtr_kernel<<<dim3(T_ / 64, H_ * 2, B_), 256, 0, stream>>>(qkv, vtg);
  attn_fa<<<dim3(T_ / 128, H_, B_), 256, 0, stream>>>(qkv, vtg, attn);
  gemm_op8<<<dim3(256), 512, 0, stream>>>(attn, wot, out, B_ * T_, D_, D_);
}

// Round 16
// 251.459 us; speedup vs baseline: 5.5093x; 5.5093x over previous
//
#include <hip/hip_runtime.h>
#include <hip/hip_bf16.h>

#define B_   2
#define T_   2048
#define D_   2048
#define H_   16
#define DH_  128
#define TD3_ 6144   // 3*D

typedef __attribute__((ext_vector_type(8))) short   short8;
typedef __attribute__((ext_vector_type(8))) unsigned short ushort8v;
typedef __attribute__((ext_vector_type(4))) float   f32x4;
typedef __attribute__((ext_vector_type(4))) float   f4v;
typedef __attribute__((ext_vector_type(4))) unsigned short u16x4;

static __device__ __forceinline__ unsigned short f2bf(float f) {
  unsigned int u = __builtin_bit_cast(unsigned int, f);
  u += 0x7FFFu + ((u >> 16) & 1u);
  return (unsigned short)(u >> 16);
}
static __device__ __forceinline__ float bf2f(unsigned short u) {
  return __builtin_bit_cast(float, (unsigned int)u << 16);
}
static __device__ __forceinline__ float fexp2(float x) {
  float r; asm("v_exp_f32 %0, %1" : "=v"(r) : "v"(x)); return r;
}

static __device__ __forceinline__ void gload_lds16(const unsigned short* g, unsigned short* l) {
  __builtin_amdgcn_global_load_lds((const __attribute__((address_space(1))) void*)g,
                                   (__attribute__((address_space(3))) void*)l, 16, 0, 0);
}

// ---------------- fp32 -> bf16 elementwise cast (vectorized) ----------------
__global__ __launch_bounds__(256) void convert_f32_bf16(const float* __restrict__ X,
                                                        unsigned short* __restrict__ Y, int n4) {
  for (int i = blockIdx.x * blockDim.x + threadIdx.x; i < n4; i += gridDim.x * blockDim.x) {
    f4v v = ((const f4v*)X)[i];
    u16x4 o;
    o[0] = f2bf(v[0]); o[1] = f2bf(v[1]); o[2] = f2bf(v[2]); o[3] = f2bf(v[3]);
    ((u16x4*)Y)[i] = o;
  }
}

// ---------------- transpose fp32 [K][N] -> bf16 [N][K] ----------------
__global__ __launch_bounds__(256) void transpose_f32_bf16(const float* __restrict__ W,
                                                          unsigned short* __restrict__ WT,
                                                          int K, int N) {
  __shared__ float tile[32][33];
  int n0 = blockIdx.x * 32, k0 = blockIdx.y * 32;
  int tx = threadIdx.x & 31, ty = threadIdx.x >> 5;
#pragma unroll
  for (int r = 0; r < 4; r++)
    tile[ty + 8 * r][tx] = W[(size_t)(k0 + ty + 8 * r) * N + n0 + tx];
  __syncthreads();
#pragma unroll
  for (int r = 0; r < 4; r++)
    WT[(size_t)(n0 + ty + 8 * r) * K + k0 + tx] = f2bf(tile[tx][ty + 8 * r]);
}

// ---------------- V transpose: qkv V-third [b][t][h*DH+dh] -> vtg [b][h][dh][t] ----------------
__global__ __launch_bounds__(256) void vtr_kernel(const unsigned short* __restrict__ qkv,
                                                  unsigned short* __restrict__ vtg) {
  __shared__ unsigned short tile[64][68];
  const int t0 = blockIdx.x * 64;
  const int h = blockIdx.y >> 1, dh0 = (blockIdx.y & 1) * 64;
  const int b = blockIdx.z;
  const int tid = threadIdx.x;
  const unsigned short* src = qkv + (size_t)b * T_ * TD3_ + 2 * D_ + h * DH_ + dh0;
  {
    const int r = tid >> 3, cc = (tid & 7) * 8;
#pragma unroll
    for (int k = 0; k < 2; k++) {
      ushort8v v = *(const ushort8v*)(src + (size_t)(t0 + k * 32 + r) * TD3_ + cc);
      *(ushort8v*)&tile[k * 32 + r][cc] = v;
    }
  }
  __syncthreads();
  unsigned short* dst = vtg + ((size_t)(b * H_ + h) * DH_ + dh0) * T_ + t0;
  {
    const int d = tid >> 3, tc = (tid & 7) * 8;
#pragma unroll
    for (int k = 0; k < 2; k++) {
      ushort8v v;
#pragma unroll
      for (int j = 0; j < 8; j++) v[j] = tile[tc + j][k * 32 + d];
      *(ushort8v*)(dst + (size_t)(k * 32 + d) * T_ + tc) = v;
    }
  }
}

// ---------------- 256x192 single-barrier software-pipelined bf16 GEMM (QKV): C bf16 ----------------
// R14 proven schedule: ONE barrier per K-tile (mid-PH_B, after vmcnt(0)).
__global__ __launch_bounds__(512, 1) void gemm_qkv192(const unsigned short* __restrict__ A,
                                                      const unsigned short* __restrict__ BT,
                                                      unsigned short* __restrict__ C,
                                                      int M, int N, int K) {
  __shared__ unsigned short lA[2][2][128 * 64];   // 64 KiB
  __shared__ unsigned short lB[2][192 * 64];      // 48 KiB

  const int tid = threadIdx.x;
  const int bid = (int)blockIdx.x;
  const int npx = 4;                              // n-tiles per XCD
  const int xcd = bid & 7, idx = bid >> 3;
  const int n0 = (xcd * npx + (idx & 3)) * 192;
  const int m0 = (idx >> 2) * 256;
  const int l = tid & 63, lr = l & 15, lg = l >> 4;
  const int wid = tid >> 6, wm = wid >> 2, wn = wid & 3;
  const int nk = K >> 6;                          // 32 (even; kt+=2 unroll relies on it)

  f32x4 acc[8][3] = {};
  short8 aQ0[4][2], aQ1[4][2], bX[3][2], bY[3][2];

  auto stageA = [&](int buf, int h, int kt) {
#pragma unroll
    for (int q = 0; q < 2; q++) {
      const int n = q * 512 + tid;
      const int row = n >> 3, ch = n & 7;
      gload_lds16(A + (size_t)(m0 + h * 128 + row) * K + kt * 64 + ((ch ^ (row & 7)) << 3),
                  &lA[buf][h][n * 8]);
    }
  };
  auto stageBt = [&](int buf, int third, int kt) {
    const int r = tid >> 3, ch = tid & 7;
    gload_lds16(BT + (size_t)(n0 + third * 64 + r) * K + kt * 64 + ((ch ^ (r & 7)) << 3),
                &lB[buf][third * 4096 + tid * 8]);
  };

#define QKV_STAGE_ALL(BUF, TT)                                                  \
  { stageA(BUF, 0, TT); stageA(BUF, 1, TT);                                     \
    stageBt(BUF, 0, TT); stageBt(BUF, 1, TT); stageBt(BUF, 2, TT); }

#define QKV_READ_A(DST, BUF, QUAD)                                              \
  _Pragma("unroll")                                                             \
  for (int mi = 0; mi < 4; mi++)                                                \
    _Pragma("unroll")                                                           \
    for (int kk = 0; kk < 2; kk++) {                                            \
      const int row = ((QUAD) * 4 + mi) * 16 + lr;                              \
      DST[mi][kk] = *(const short8*)&lA[BUF][wm][row * 64 +                     \
                      (((kk * 4 + lg) ^ (lr & 7)) << 3)];                       \
    }

#define QKV_READ_B(DST, BUF)                                                    \
  _Pragma("unroll")                                                             \
  for (int ni = 0; ni < 3; ni++)                                                \
    _Pragma("unroll")                                                           \
    for (int kk = 0; kk < 2; kk++) {                                            \
      const int row = wn * 48 + ni * 16 + lr;                                   \
      DST[ni][kk] = *(const short8*)&lB[BUF][row * 64 +                         \
                      (((kk * 4 + lg) ^ (lr & 7)) << 3)];                       \
    }

// PH_A(t): stage ALL(t+1)->buf^1; read aQ1(buf); 24 MFMA. NO barrier.
#define QKV_PHASE_A(BUF, BCUR, TT)                                              \
  {                                                                             \
    if ((TT) + 1 < nk) QKV_STAGE_ALL(1 - (BUF), (TT) + 1);                      \
    QKV_READ_A(aQ1, BUF, 1)                                                     \
    __builtin_amdgcn_s_setprio(1);                                              \
    _Pragma("unroll")                                                           \
    for (int mi = 0; mi < 4; mi++)                                              \
      _Pragma("unroll")                                                         \
      for (int ni = 0; ni < 3; ni++)                                            \
        _Pragma("unroll")                                                       \
        for (int kk = 0; kk < 2; kk++)                                          \
          acc[mi][ni] = __builtin_amdgcn_mfma_f32_16x16x32_bf16(                \
              aQ0[mi][kk], BCUR[ni][kk], acc[mi][ni], 0, 0, 0);                 \
    __builtin_amdgcn_s_setprio(0);                                              \
  }

// PH_B(t): 16 MFMA; vmcnt(0); THE barrier; prefetch (t+1) frags; 8 MFMA. NO trailing barrier.
#define QKV_PHASE_B(BUF, BCUR, BNXT, TT)                                        \
  {                                                                             \
    __builtin_amdgcn_s_setprio(1);                                              \
    _Pragma("unroll")                                                           \
    for (int mi = 0; mi < 4; mi++)                                              \
      _Pragma("unroll")                                                         \
      for (int ni = 0; ni < 2; ni++)                                            \
        _Pragma("unroll")                                                       \
        for (int kk = 0; kk < 2; kk++)                                          \
          acc[4 + mi][ni] = __builtin_amdgcn_mfma_f32_16x16x32_bf16(            \
              aQ1[mi][kk], BCUR[ni][kk], acc[4 + mi][ni], 0, 0, 0);             \
    __builtin_amdgcn_s_setprio(0);                                              \
    asm volatile("s_waitcnt vmcnt(0)" ::: "memory");                            \
    __builtin_amdgcn_s_barrier();                                               \
    __builtin_amdgcn_sched_barrier(0);                                          \
    if ((TT) + 1 < nk) {                                                        \
      QKV_READ_A(aQ0, 1 - (BUF), 0)                                             \
      QKV_READ_B(BNXT, 1 - (BUF))                                               \
    }                                                                           \
    __builtin_amdgcn_s_setprio(1);                                              \
    _Pragma("unroll")                                                           \
    for (int mi = 0; mi < 4; mi++)                                              \
      _Pragma("unroll")                                                         \
      for (int kk = 0; kk < 2; kk++)                                            \
        acc[4 + mi][2] = __builtin_amdgcn_mfma_f32_16x16x32_bf16(               \
            aQ1[mi][kk], BCUR[2][kk], acc[4 + mi][2], 0, 0, 0);                 \
    __builtin_amdgcn_s_setprio(0);                                              \
  }

  // ---- prologue: stage tile0, drain, load tile0 frags ----
  QKV_STAGE_ALL(0, 0)
  asm volatile("s_waitcnt vmcnt(0)" ::: "memory");
  __builtin_amdgcn_s_barrier();
  __builtin_amdgcn_sched_barrier(0);
  QKV_READ_A(aQ0, 0, 0)
  QKV_READ_B(bX, 0)

  for (int kt = 0; kt < nk; kt += 2) {
    QKV_PHASE_A(0, bX, kt)
    QKV_PHASE_B(0, bX, bY, kt)
    QKV_PHASE_A(1, bY, kt + 1)
    QKV_PHASE_B(1, bY, bX, kt + 1)
  }

#pragma unroll
  for (int mi = 0; mi < 8; mi++)
#pragma unroll
    for (int ni = 0; ni < 3; ni++)
#pragma unroll
      for (int i = 0; i < 4; i++) {
        const int row = m0 + wm * 128 + mi * 16 + lg * 4 + i;
        const int col = n0 + wn * 48 + ni * 16 + lr;
        C[(size_t)row * N + col] = f2bf(acc[mi][ni][i]);
      }
#undef QKV_PHASE_B
#undef QKV_PHASE_A
#undef QKV_READ_B
#undef QKV_READ_A
#undef QKV_STAGE_ALL
}

// ---------------- 128x256 single-barrier bf16 GEMM (output proj): C fp32 ----------------
__global__ __launch_bounds__(512, 1) void gemm_op8(const unsigned short* __restrict__ A,
                                                   const unsigned short* __restrict__ BT,
                                                   float* __restrict__ C,
                                                   int M, int N, int K) {
  __shared__ unsigned short lA[2][128 * 64];      // 32 KiB
  __shared__ unsigned short lB[2][2][128 * 64];   // 64 KiB

  const int tid = threadIdx.x;
  const int bid = (int)blockIdx.x;
  const int xcd = bid & 7, idx = bid >> 3;        // N/256 == 8 n-tiles: one per XCD
  const int n0 = xcd * 256, m0 = idx * 128;
  const int l = tid & 63, lr = l & 15, lg = l >> 4;
  const int wid = tid >> 6, wm = wid >> 2, wn = wid & 3;
  const int bh = wn >> 1, br0 = (wn & 1) * 64;
  const int nk = K >> 6;                          // 32 (even)

  f32x4 acc[4][4] = {};
  short8 aLO[2][2], aHI[2][2], b[4][2];

  auto stageA = [&](int buf, int kt) {
#pragma unroll
    for (int q = 0; q < 2; q++) {
      const int n = q * 512 + tid;
      const int row = n >> 3, ch = n & 7;
      gload_lds16(A + (size_t)(m0 + row) * K + kt * 64 + ((ch ^ (row & 7)) << 3),
                  &lA[buf][n * 8]);
    }
  };
  auto stageB = [&](int buf, int h, int kt) {
#pragma unroll
    for (int q = 0; q < 2; q++) {
      const int n = q * 512 + tid;
      const int row = n >> 3, ch = n & 7;
      gload_lds16(BT + (size_t)(n0 + h * 128 + row) * K + kt * 64 + ((ch ^ (row & 7)) << 3),
                  &lB[buf][h][n * 8]);
    }
  };

#define OP_STAGE_ALL(BUF, TT)                                                   \
  { stageB(BUF, 0, TT); stageB(BUF, 1, TT); stageA(BUF, TT); }

#define OP_READ_A(DST, BUF, HALF)                                               \
  _Pragma("unroll")                                                             \
  for (int mi = 0; mi < 2; mi++)                                                \
    _Pragma("unroll")                                                           \
    for (int kk = 0; kk < 2; kk++) {                                            \
      const int row = wm * 64 + ((HALF) * 2 + mi) * 16 + lr;                    \
      DST[mi][kk] = *(const short8*)&lA[BUF][row * 64 +                         \
                      (((kk * 4 + lg) ^ (lr & 7)) << 3)];                       \
    }

#define OP_READ_B(BUF)                                                          \
  _Pragma("unroll")                                                             \
  for (int ni = 0; ni < 4; ni++)                                                \
    _Pragma("unroll")                                                           \
    for (int kk = 0; kk < 2; kk++) {                                            \
      const int row = br0 + ni * 16 + lr;                                       \
      b[ni][kk] = *(const short8*)&lB[BUF][bh][row * 64 +                       \
                      (((kk * 4 + lg) ^ (lr & 7)) << 3)];                       \
    }

  // ---- prologue ----
  OP_STAGE_ALL(0, 0)
  asm volatile("s_waitcnt vmcnt(0)" ::: "memory");
  __builtin_amdgcn_s_barrier();
  __builtin_amdgcn_sched_barrier(0);
  OP_READ_A(aLO, 0, 0)
  OP_READ_B(0)

  for (int kt = 0; kt < nk; kt++) {
    const int buf = kt & 1;

    // PH_A: stage all (t+1)->buf^1; read aHI(buf); 16 MFMA (aLO x b[0..3]). NO barrier.
    if (kt + 1 < nk) OP_STAGE_ALL(buf ^ 1, kt + 1)
    OP_READ_A(aHI, buf, 1)
    __builtin_amdgcn_s_setprio(1);
#pragma unroll
    for (int mi = 0; mi < 2; mi++)
#pragma unroll
      for (int ni = 0; ni < 4; ni++)
#pragma unroll
        for (int kk = 0; kk < 2; kk++)
          acc[mi][ni] = __builtin_amdgcn_mfma_f32_16x16x32_bf16(aLO[mi][kk], b[ni][kk], acc[mi][ni], 0, 0, 0);
    __builtin_amdgcn_s_setprio(0);

    // PH_B: 8 MFMA (aHI x b[0..1]); vmcnt(0); THE barrier; prefetch (t+1) frags;
    //       8 MFMA (aHI x b[2..3]). NO trailing barrier.
    __builtin_amdgcn_s_setprio(1);
#pragma unroll
    for (int mi = 0; mi < 2; mi++)
#pragma unroll
      for (int ni = 0; ni < 2; ni++)
#pragma unroll
        for (int kk = 0; kk < 2; kk++)
          acc[2 + mi][ni] = __builtin_amdgcn_mfma_f32_16x16x32_bf16(aHI[mi][kk], b[ni][kk], acc[2 + mi][ni], 0, 0, 0);
    __builtin_amdgcn_s_setprio(0);
    asm volatile("s_waitcnt vmcnt(0)" ::: "memory");
    __builtin_amdgcn_s_barrier();
    __builtin_amdgcn_sched_barrier(0);
    short8 bsav2[2][2];
#pragma unroll
    for (int ni = 0; ni < 2; ni++)
#pragma unroll
      for (int kk = 0; kk < 2; kk++) bsav2[ni][kk] = b[2 + ni][kk];
    if (kt + 1 < nk) {
      OP_READ_A(aLO, buf ^ 1, 0)
      OP_READ_B(buf ^ 1)
    }
    __builtin_amdgcn_s_setprio(1);
#pragma unroll
    for (int mi = 0; mi < 2; mi++)
#pragma unroll
      for (int ni = 0; ni < 2; ni++)
#pragma unroll
        for (int kk = 0; kk < 2; kk++)
          acc[2 + mi][2 + ni] = __builtin_amdgcn_mfma_f32_16x16x32_bf16(aHI[mi][kk], bsav2[ni][kk], acc[2 + mi][2 + ni], 0, 0, 0);
    __builtin_amdgcn_s_setprio(0);
  }

#pragma unroll
  for (int mi = 0; mi < 4; mi++)
#pragma unroll
    for (int ni = 0; ni < 4; ni++)
#pragma unroll
      for (int i = 0; i < 4; i++) {
        const int row = m0 + wm * 64 + mi * 16 + lg * 4 + i;
        const int col = n0 + wn * 64 + ni * 16 + lr;
        C[(size_t)row * N + col] = acc[mi][ni][i];
      }
#undef OP_READ_B
#undef OP_READ_A
#undef OP_STAGE_ALL
}

// ---------------- flash attention (causal), QBLK=128, KVBLK=64, 2-phase pipeline ----------------
__global__ __launch_bounds__(256, 2) void attn_fa(const unsigned short* __restrict__ qkv,
                                                  const unsigned short* __restrict__ vtg,
                                                  unsigned short* __restrict__ out) {
  const int x = blockIdx.x, h = blockIdx.y, b = blockIdx.z;
  const int qtl = b ? x : (T_ / 128 - 1 - x);
  const int q0 = qtl * 128;
  const int tid = threadIdx.x, w = tid >> 6, l = tid & 63, lr = l & 15, lg = l >> 4;

  const unsigned short* Qb = qkv + (size_t)b * T_ * TD3_ + h * DH_;
  const unsigned short* Kb = Qb + D_;
  const unsigned short* Vt = vtg + ((size_t)b * H_ + h) * DH_ * T_;

  __shared__ unsigned short klds[2][64 * 128];
  __shared__ unsigned short vt[2][128 * 64];
  __shared__ unsigned short plds[4][32 * 64];

  const float scale2 = 0.12751744519764462f;     // log2(e)/sqrt(128)

  short8 qf[2][4];
#pragma unroll
  for (int mi = 0; mi < 2; mi++) {
    const unsigned short* qrow = Qb + (size_t)(q0 + w * 32 + mi * 16 + lr) * TD3_;
#pragma unroll
    for (int ks = 0; ks < 4; ks++) {
      ushort8v qv = *(const ushort8v*)(qrow + ks * 32 + lg * 8);
      short8 qs;
#pragma unroll
      for (int j = 0; j < 8; j++) qs[j] = (short)f2bf(bf2f(qv[j]) * scale2);
      qf[mi][ks] = qs;
    }
  }

  f32x4 oacc[2][8] = {};
  float mrun[2][4], rsuml[2][4];
#pragma unroll
  for (int mi = 0; mi < 2; mi++)
#pragma unroll
    for (int i = 0; i < 4; i++) { mrun[mi][i] = -__builtin_inff(); rsuml[mi][i] = 0.f; }

  auto STAGE = [&](int buf, int kv0) {
#pragma unroll
    for (int it = 0; it < 4; it++) {
      const int n = it * 256 + tid;
      { const int kv = n >> 4, ch = n & 15;
        gload_lds16(Kb + (size_t)(kv0 + kv) * TD3_ + ((ch ^ (kv & 7)) << 3),
                    &klds[buf][n * 8]); }
      { const int dh = n >> 3, ch = n & 7;
        gload_lds16(Vt + (size_t)dh * T_ + kv0 + ((ch ^ (dh & 7)) << 3),
                    &vt[buf][n * 8]); }
    }
  };

  const int nt = 2 * qtl + 2;
  STAGE(0, 0);
  __syncthreads();

  for (int t = 0; t < nt; t++) {
    const int buf = t & 1;
    if (t + 1 < nt) STAGE(buf ^ 1, (t + 1) * 64);

    const int kv0 = t * 64;
    const bool active = (kv0 <= q0 + w * 32 + 31);
    if (active) {
      // ---- S = Q K^T (log2 domain) ----
      f32x4 s[2][4] = {};
      __builtin_amdgcn_s_setprio(1);
#pragma unroll
      for (int nf = 0; nf < 4; nf++) {
        const int kv = nf * 16 + lr;
#pragma unroll
        for (int ks = 0; ks < 4; ks++) {
          short8 kf = *(const short8*)&klds[buf][kv * 128 + (((ks * 4 + lg) ^ (lr & 7)) << 3)];
#pragma unroll
          for (int mi = 0; mi < 2; mi++)
            s[mi][nf] = __builtin_amdgcn_mfma_f32_16x16x32_bf16(qf[mi][ks], kf, s[mi][nf], 0, 0, 0);
        }
      }
      __builtin_amdgcn_s_setprio(0);

      // ---- causal mask + per-lane max ----
      const bool needmask = (kv0 + 63 > q0 + w * 32);
      float pmax[2][4];
#pragma unroll
      for (int mi = 0; mi < 2; mi++)
#pragma unroll
        for (int i = 0; i < 4; i++) pmax[mi][i] = -__builtin_inff();
#pragma unroll
      for (int mi = 0; mi < 2; mi++)
#pragma unroll
        for (int nf = 0; nf < 4; nf++)
#pragma unroll
          for (int i = 0; i < 4; i++) {
            float xv = s[mi][nf][i];
            if (needmask) {
              const int qr = w * 32 + mi * 16 + lg * 4 + i;
              const int kc = nf * 16 + lr;
              if (kv0 + kc > q0 + qr) xv = -__builtin_inff();
            }
            s[mi][nf][i] = xv;
            pmax[mi][i] = fmaxf(pmax[mi][i], xv);
          }

      // ---- defer-max ----
      int ok = 1;
#pragma unroll
      for (int mi = 0; mi < 2; mi++)
#pragma unroll
        for (int i = 0; i < 4; i++)
          ok &= (pmax[mi][i] <= mrun[mi][i] + 8.0f) ? 1 : 0;

      if (!__all(ok)) {
#pragma unroll
        for (int m = 1; m < 16; m <<= 1)
#pragma unroll
          for (int mi = 0; mi < 2; mi++)
#pragma unroll
            for (int i = 0; i < 4; i++)
              pmax[mi][i] = fmaxf(pmax[mi][i], __shfl_xor(pmax[mi][i], m));
#pragma unroll
        for (int mi = 0; mi < 2; mi++)
#pragma unroll
          for (int i = 0; i < 4; i++) {
            const float mn = fmaxf(mrun[mi][i], pmax[mi][i]);
            const float al = fexp2(mrun[mi][i] - mn);
            mrun[mi][i] = mn;
            rsuml[mi][i] *= al;
#pragma unroll
            for (int nf = 0; nf < 8; nf++) oacc[mi][nf][i] *= al;
          }
      }

      // ---- P = exp2(S - m); per-lane rsum; P -> LDS ----
#pragma unroll
      for (int mi = 0; mi < 2; mi++)
#pragma unroll
        for (int nf = 0; nf < 4; nf++)
#pragma unroll
          for (int i = 0; i < 4; i++) {
            const float p = fexp2(s[mi][nf][i] - mrun[mi][i]);
            rsuml[mi][i] += p;
            const int prow = mi * 16 + lg * 4 + i;
            plds[w][prow * 64 + ((nf * 16 + lr) ^ ((prow & 7) << 3))] = f2bf(p);
          }

      // ---- O += P V ----
      __builtin_amdgcn_s_setprio(1);
#pragma unroll
      for (int kk = 0; kk < 2; kk++) {
        short8 pa[2];
#pragma unroll
        for (int mi = 0; mi < 2; mi++) {
          const int prow = mi * 16 + lr;
          pa[mi] = *(const short8*)&plds[w][prow * 64 + (((kk * 32 + lg * 8)) ^ ((prow & 7) << 3))];
        }
#pragma unroll
        for (int nf = 0; nf < 8; nf++) {
          const short8 vb = *(const short8*)&vt[buf][(nf * 16 + lr) * 64 + (((kk * 4 + lg) ^ (lr & 7)) << 3)];
#pragma unroll
          for (int mi = 0; mi < 2; mi++)
            oacc[mi][nf] = __builtin_amdgcn_mfma_f32_16x16x32_bf16(pa[mi], vb, oacc[mi][nf], 0, 0, 0);
        }
      }
      __builtin_amdgcn_s_setprio(0);
    }
    __syncthreads();
  }

  // ---- final rsum reduce + normalize + write ----
#pragma unroll
  for (int m = 1; m < 16; m <<= 1)
#pragma unroll
    for (int mi = 0; mi < 2; mi++)
#pragma unroll
      for (int i = 0; i < 4; i++) rsuml[mi][i] += __shfl_xor(rsuml[mi][i], m);

  float rinv[2][4];
#pragma unroll
  for (int mi = 0; mi < 2; mi++)
#pragma unroll
    for (int i = 0; i < 4; i++) rinv[mi][i] = 1.f / rsuml[mi][i];
#pragma unroll
  for (int mi = 0; mi < 2; mi++) {
    unsigned short* orow = out + ((size_t)b * T_ + q0 + w * 32 + mi * 16 + lg * 4) * D_ + h * DH_;
#pragma unroll
    for (int nf = 0; nf < 8; nf++)
#pragma unroll
      for (int i = 0; i < 4; i++)
        orow[(size_t)i * D_ + nf * 16 + lr] = f2bf(oacc[mi][nf][i] * rinv[mi][i]);
  }
}

extern "C" void kernel_launch(void* const* d_in, const int* in_sizes, int n_in,
                              void* d_out, int out_size, void* d_ws, size_t ws_size,
                              hipStream_t stream) {
  const float* x    = (const float*)d_in[0];
  const float* wqkv = (const float*)d_in[1];
  const float* wo   = (const float*)d_in[2];
  float* out = (float*)d_out;

  char* ws = (char*)d_ws;
  unsigned short* xb    = (unsigned short*)(ws);               // 16.8 MB (reused as attn out)
  unsigned short* wqkvt = (unsigned short*)(ws + 16777216);    // 25.2 MB (dead after gemm1)
  unsigned short* vtg   = (unsigned short*)(ws + 16777216);    // 16.8 MB, overlays wqkvt
  unsigned short* wot   = (unsigned short*)(ws + 41943040);    //  8.4 MB
  unsigned short* qkv   = (unsigned short*)(ws + 50331648);    // 50.3 MB  (end 100.7 MB)
  unsigned short* attn  = xb;   // xb dead after GEMM1

  convert_f32_bf16<<<2048, 256, 0, stream>>>(x, xb, B_ * T_ * D_ / 4);
  transpose_f32_bf16<<<dim3(TD3_ / 32, D_ / 32), 256, 0, stream>>>(wqkv, wqkvt, D_, TD3_);
  transpose_f32_bf16<<<dim3(D_ / 32, D_ / 32), 256, 0, stream>>>(wo, wot, D_, D_);

  gemm_qkv192<<<dim3(512), 512, 0, stream>>>(xb, wqkvt, qkv, B_ * T_, TD3_, D_);
  vtr_kernel<<<dim3(T_ / 64, H_ * 2, B_), 256, 0, stream>>>(qkv, vtg);
  attn_fa<<<dim3(T_ / 128, H_, B_), 256, 0, stream>>>(qkv, vtg, attn);
  gemm_op8<<<dim3(256), 512, 0, stream>>>(attn, wot, out, B_ * T_, D_, D_);
}